// Round 1
// baseline (556.771 us; speedup 1.0000x reference)
//
#include <hip/hip_runtime.h>
#include <hip/hip_bf16.h>
#include <cstdint>

typedef __bf16 bf16;
typedef __bf16 bf16_8 __attribute__((ext_vector_type(8)));
typedef __bf16 bf16_4 __attribute__((ext_vector_type(4)));
typedef float f32_4 __attribute__((ext_vector_type(4)));

#define MFMA_16x16x32(a, b, c) __builtin_amdgcn_mfma_f32_16x16x32_bf16((a), (b), (c), 0, 0, 0)

__device__ __forceinline__ void gll16(const void* g, void* l) {
  __builtin_amdgcn_global_load_lds((const __attribute__((address_space(1))) void*)g,
                                   (__attribute__((address_space(3))) void*)l, 16, 0, 0);
}

__device__ __forceinline__ bf16_8 cvt_bf8(float4 a, float4 b) {
  bf16_8 r;
  r[0] = (bf16)a.x; r[1] = (bf16)a.y; r[2] = (bf16)a.z; r[3] = (bf16)a.w;
  r[4] = (bf16)b.x; r[5] = (bf16)b.y; r[6] = (bf16)b.z; r[7] = (bf16)b.w;
  return r;
}

// ---------------- weight fp32 -> bf16 conversion (4 matrices, 1M elems each) --
__global__ __launch_bounds__(256) void convert4(const float* __restrict__ w0,
                                                const float* __restrict__ w1,
                                                const float* __restrict__ w2,
                                                const float* __restrict__ w3,
                                                bf16* __restrict__ out, int per) {
  const float* srcs[4] = {w0, w1, w2, w3};
  const float* src = srcs[blockIdx.y];
  bf16* dst = out + (size_t)blockIdx.y * per;
  int i = (blockIdx.x * 256 + threadIdx.x) * 4;
  float4 f = *(const float4*)(src + i);
  bf16_4 v;
  v[0] = (bf16)f.x; v[1] = (bf16)f.y; v[2] = (bf16)f.z; v[3] = (bf16)f.w;
  *(bf16_4*)(dst + i) = v;
}

// ---------------- GEMM: C[M][N] = A[M][K] * Bt[N][K]^T  (torch Linear) -------
// 128x128 block tile, BK=32, 256 threads = 4 waves in 2x2, each wave 64x64.
template <bool A_F32, bool OUT_F32>
__global__ __launch_bounds__(256) void gemm_bt(const void* __restrict__ Ap,
                                               const bf16* __restrict__ Bt,
                                               void* __restrict__ Cp,
                                               int M, int N, int K) {
  constexpr int BM = 128, BN = 128, BK = 32;
  constexpr int AST = A_F32 ? 40 : 32;  // pad manual-staged A to kill bank conflicts
  __shared__ alignas(16) bf16 As[BM * AST];
  __shared__ alignas(16) bf16 Bs[BN * BK];

  const int tid = threadIdx.x;
  const int wave = tid >> 6, lane = tid & 63;
  const int quad = lane >> 4, l15 = lane & 15;
  const int wm = (wave & 1) * 64, wn = (wave >> 1) * 64;
  const size_t m0 = (size_t)blockIdx.x * BM;
  const size_t n0 = (size_t)blockIdx.y * BN;

  f32_4 acc[4][4] = {};

  // B staging via global_load_lds: wave w covers rows [32w, 32w+32)
  const bf16* Bg = Bt + (n0 + wave * 32 + (lane >> 2)) * (size_t)K + (lane & 3) * 8;
  bf16* Bl = Bs + (wave * 32 + (lane >> 2)) * BK + (lane & 3) * 8;

  const float* Af = nullptr;
  bf16* Al = nullptr;
  const bf16* Ag = nullptr;
  bf16* Al2 = nullptr;
  if constexpr (A_F32) {
    Af = (const float*)Ap + (m0 + (tid >> 1)) * (size_t)K + (tid & 1) * 16;
    Al = As + (tid >> 1) * AST + (tid & 1) * 16;
  } else {
    Ag = (const bf16*)Ap + (m0 + wave * 32 + (lane >> 2)) * (size_t)K + (lane & 3) * 8;
    Al2 = As + (wave * 32 + (lane >> 2)) * AST + (lane & 3) * 8;
  }

  for (int k0 = 0; k0 < K; k0 += BK) {
    if constexpr (A_F32) {
      float4 f0 = *(const float4*)(Af + k0);
      float4 f1 = *(const float4*)(Af + k0 + 4);
      float4 f2 = *(const float4*)(Af + k0 + 8);
      float4 f3 = *(const float4*)(Af + k0 + 12);
      *(bf16_8*)Al = cvt_bf8(f0, f1);
      *(bf16_8*)(Al + 8) = cvt_bf8(f2, f3);
    } else {
      gll16(Ag + k0, Al2);
      gll16(Ag + 16 * (size_t)K + k0, Al2 + 16 * AST);
    }
    gll16(Bg + k0, Bl);
    gll16(Bg + 16 * (size_t)K + k0, Bl + 16 * BK);
    __syncthreads();

    bf16_8 af[4], bfr[4];
#pragma unroll
    for (int mt = 0; mt < 4; ++mt)
      af[mt] = *(const bf16_8*)&As[(wm + mt * 16 + l15) * AST + quad * 8];
#pragma unroll
    for (int nt = 0; nt < 4; ++nt)
      bfr[nt] = *(const bf16_8*)&Bs[(wn + nt * 16 + l15) * BK + quad * 8];
#pragma unroll
    for (int mt = 0; mt < 4; ++mt)
#pragma unroll
      for (int nt = 0; nt < 4; ++nt)
        acc[mt][nt] = MFMA_16x16x32(af[mt], bfr[nt], acc[mt][nt]);
    __syncthreads();
  }

  if constexpr (OUT_F32) {
    float* C = (float*)Cp;
#pragma unroll
    for (int mt = 0; mt < 4; ++mt)
#pragma unroll
      for (int i = 0; i < 4; ++i) {
        size_t row = m0 + wm + mt * 16 + quad * 4 + i;
        float* cr = C + row * N + n0 + wn + l15;
#pragma unroll
        for (int nt = 0; nt < 4; ++nt) cr[nt * 16] = acc[mt][nt][i];
      }
  } else {
    bf16* C = (bf16*)Cp;
#pragma unroll
    for (int mt = 0; mt < 4; ++mt)
#pragma unroll
      for (int i = 0; i < 4; ++i) {
        size_t row = m0 + wm + mt * 16 + quad * 4 + i;
        bf16* cr = C + row * N + n0 + wn + l15;
#pragma unroll
        for (int nt = 0; nt < 4; ++nt) cr[nt * 16] = (bf16)acc[mt][nt][i];
      }
  }
}

// ---------------- fused flash attention, one (b,h) x 64 q-rows per block -----
__global__ __launch_bounds__(256) void attn_fused(const bf16* __restrict__ Q,
                                                  const bf16* __restrict__ K,
                                                  const bf16* __restrict__ V,
                                                  const unsigned char* __restrict__ mask,
                                                  const float* __restrict__ gamma,
                                                  bf16* __restrict__ Out) {
  constexpr int S = 2048, E = 1024, Dh = 64;
  constexpr float scale = 0.125f;  // 1/sqrt(64)
  const int q0 = blockIdx.x * 64;
  const int b = blockIdx.y >> 4, h = blockIdx.y & 15;
  const int tid = threadIdx.x;
  const int wave = tid >> 6, lane = tid & 63;
  const int quad = lane >> 4, l15 = lane & 15;

  __shared__ alignas(16) bf16 Qs[64 * 72];
  __shared__ alignas(16) bf16 Ks[64 * 72];
  __shared__ alignas(16) bf16 Vt[64 * 72];  // transposed: [d][kj]
  __shared__ alignas(16) bf16 Ps[64 * 72];

  const size_t bSE = (size_t)b * S * E;
  const bf16* Qg = Q + bSE + (size_t)q0 * E + h * Dh;
  const bf16* Kg = K + bSE + h * Dh;
  const bf16* Vg = V + bSE + h * Dh;
  const unsigned char* mg = mask + (size_t)b * S;

  {  // stage Q once: 64 rows x 64 cols
    const int r = tid >> 2, c = (tid & 3) * 16;
    const bf16* src = Qg + (size_t)r * E + c;
    *(bf16_8*)&Qs[r * 72 + c] = *(const bf16_8*)src;
    *(bf16_8*)&Qs[r * 72 + c + 8] = *(const bf16_8*)(src + 8);
  }

  f32_4 accO[4] = {};
  float m_i[4] = {-3.0e38f, -3.0e38f, -3.0e38f, -3.0e38f};
  float l_i[4] = {0.f, 0.f, 0.f, 0.f};

  for (int kt = 0; kt < S; kt += 64) {
    __syncthreads();  // protect Ks/Vt (prev iter readers) + Q visibility (1st)
    {
      const int r = tid >> 2, c = (tid & 3) * 16;
      const bf16* src = Kg + (size_t)(kt + r) * E + c;
      *(bf16_8*)&Ks[r * 72 + c] = *(const bf16_8*)src;
      *(bf16_8*)&Ks[r * 72 + c + 8] = *(const bf16_8*)(src + 8);
    }
    {  // V staged transposed
      const int r = tid & 63, c0 = (tid >> 6) * 16;
      const bf16* src = Vg + (size_t)(kt + r) * E + c0;
      bf16_8 u0 = *(const bf16_8*)src;
      bf16_8 u1 = *(const bf16_8*)(src + 8);
#pragma unroll
      for (int j = 0; j < 8; ++j) Vt[(c0 + j) * 72 + r] = u0[j];
#pragma unroll
      for (int j = 0; j < 8; ++j) Vt[(c0 + 8 + j) * 72 + r] = u1[j];
    }
    __syncthreads();

    float bias[4];
#pragma unroll
    for (int t = 0; t < 4; ++t)
      bias[t] = mg[kt + t * 16 + l15] ? -1.0e30f : 0.0f;

    // S tile: wave's 16 q-rows x 64 keys
    f32_4 sAcc[4] = {};
#pragma unroll
    for (int ks = 0; ks < 2; ++ks) {
      bf16_8 a = *(const bf16_8*)&Qs[(wave * 16 + l15) * 72 + ks * 32 + quad * 8];
#pragma unroll
      for (int t = 0; t < 4; ++t) {
        bf16_8 bb = *(const bf16_8*)&Ks[(t * 16 + l15) * 72 + ks * 32 + quad * 8];
        sAcc[t] = MFMA_16x16x32(a, bb, sAcc[t]);
      }
    }

    // online softmax; lane holds rows quad*4+i, cols t*16+l15
    float p[4][4];
#pragma unroll
    for (int i = 0; i < 4; ++i) {
      float s0 = sAcc[0][i] * scale + bias[0];
      float s1 = sAcc[1][i] * scale + bias[1];
      float s2 = sAcc[2][i] * scale + bias[2];
      float s3 = sAcc[3][i] * scale + bias[3];
      float mrow = fmaxf(fmaxf(s0, s1), fmaxf(s2, s3));
      mrow = fmaxf(mrow, __shfl_xor(mrow, 1));
      mrow = fmaxf(mrow, __shfl_xor(mrow, 2));
      mrow = fmaxf(mrow, __shfl_xor(mrow, 4));
      mrow = fmaxf(mrow, __shfl_xor(mrow, 8));
      float mn = fmaxf(m_i[i], mrow);
      float alpha = __expf(m_i[i] - mn);
      m_i[i] = mn;
      float p0 = __expf(s0 - mn), p1 = __expf(s1 - mn);
      float p2 = __expf(s2 - mn), p3 = __expf(s3 - mn);
      p[0][i] = p0; p[1][i] = p1; p[2][i] = p2; p[3][i] = p3;
      float rs = p0 + p1 + p2 + p3;
      rs += __shfl_xor(rs, 1);
      rs += __shfl_xor(rs, 2);
      rs += __shfl_xor(rs, 4);
      rs += __shfl_xor(rs, 8);
      l_i[i] = l_i[i] * alpha + rs;
#pragma unroll
      for (int t = 0; t < 4; ++t) accO[t][i] *= alpha;
    }

    // P: C-layout -> LDS -> A-layout (wave-private 16-row region)
    bf16* Pw = Ps + wave * 16 * 72;
#pragma unroll
    for (int i = 0; i < 4; ++i)
#pragma unroll
      for (int t = 0; t < 4; ++t)
        Pw[(quad * 4 + i) * 72 + t * 16 + l15] = (bf16)p[t][i];
    __syncthreads();

    // O += P @ V
#pragma unroll
    for (int ks = 0; ks < 2; ++ks) {
      bf16_8 a = *(const bf16_8*)&Pw[l15 * 72 + ks * 32 + quad * 8];
#pragma unroll
      for (int t = 0; t < 4; ++t) {
        bf16_8 bb = *(const bf16_8*)&Vt[(t * 16 + l15) * 72 + ks * 32 + quad * 8];
        accO[t] = MFMA_16x16x32(a, bb, accO[t]);
      }
    }
  }

  const float g = gamma[h];
#pragma unroll
  for (int i = 0; i < 4; ++i) {
    float inv = g / l_i[i];
    bf16* orow = Out + ((size_t)(b * S + q0 + wave * 16 + quad * 4 + i)) * E + h * Dh + l15;
#pragma unroll
    for (int t = 0; t < 4; ++t) orow[t * 16] = (bf16)(accO[t][i] * inv);
  }
}

// ---------------- launch ------------------------------------------------------
extern "C" void kernel_launch(void* const* d_in, const int* in_sizes, int n_in,
                              void* d_out, int out_size, void* d_ws, size_t ws_size,
                              hipStream_t stream) {
  constexpr int Bb = 4, S = 2048, E = 1024;
  constexpr int M = Bb * S;  // 8192

  const float* q = (const float*)d_in[0];
  const float* k = (const float*)d_in[1];
  const float* v = (const float*)d_in[2];
  const unsigned char* mask = (const unsigned char*)d_in[3];
  const float* Wq = (const float*)d_in[4];
  const float* Wk = (const float*)d_in[5];
  const float* Wv = (const float*)d_in[6];
  const float* Wo = (const float*)d_in[7];
  const float* gamma = (const float*)d_in[8];

  // workspace layout (72 MiB total):
  // [0,8M): Wq,Wk,Wv,Wo bf16 (2 MiB each); [8M,24M): Q; [24M,40M): K;
  // [40M,56M): V; [56M,72M): attn_out  (all bf16 [M][E])
  char* ws = (char*)d_ws;
  bf16* Wb = (bf16*)ws;
  bf16* Qb = (bf16*)(ws + ((size_t)8 << 20));
  bf16* Kb = (bf16*)(ws + ((size_t)24 << 20));
  bf16* Vb = (bf16*)(ws + ((size_t)40 << 20));
  bf16* At = (bf16*)(ws + ((size_t)56 << 20));

  convert4<<<dim3(1024, 4), 256, 0, stream>>>(Wq, Wk, Wv, Wo, Wb, 1 << 20);

  dim3 ggrid(M / 128, E / 128);
  gemm_bt<true, false><<<ggrid, 256, 0, stream>>>(q, Wb, Qb, M, E, E);
  gemm_bt<true, false><<<ggrid, 256, 0, stream>>>(k, Wb + (1 << 20), Kb, M, E, E);
  gemm_bt<true, false><<<ggrid, 256, 0, stream>>>(v, Wb + (2 << 20), Vb, M, E, E);

  attn_fused<<<dim3(S / 64, Bb * 16), 256, 0, stream>>>(Qb, Kb, Vb, mask, gamma, At);

  gemm_bt<false, true><<<ggrid, 256, 0, stream>>>(At, Wb + (3 << 20), d_out, M, E, E);
}

// Round 2
// 417.309 us; speedup vs baseline: 1.3342x; 1.3342x over previous
//
#include <hip/hip_runtime.h>
#include <hip/hip_bf16.h>
#include <cstdint>

typedef __bf16 bf16;
typedef __bf16 bf16_8 __attribute__((ext_vector_type(8)));
typedef __bf16 bf16_4 __attribute__((ext_vector_type(4)));
typedef float f32_4 __attribute__((ext_vector_type(4)));

#define MFMA_16x16x32(a, b, c) __builtin_amdgcn_mfma_f32_16x16x32_bf16((a), (b), (c), 0, 0, 0)

__device__ __forceinline__ void gll16(const void* g, void* l) {
  __builtin_amdgcn_global_load_lds((const __attribute__((address_space(1))) void*)g,
                                   (__attribute__((address_space(3))) void*)l, 16, 0, 0);
}

__device__ __forceinline__ float exp2fast(float x) {
#if __has_builtin(__builtin_amdgcn_exp2f)
  return __builtin_amdgcn_exp2f(x);
#else
  return __exp2f(x);
#endif
}

__device__ __forceinline__ unsigned bfbits(float x) {
  bf16 b = (bf16)x;
  return (unsigned)__builtin_bit_cast(unsigned short, b);
}

// ---------------- fp32 -> bf16 converters -----------------------------------
__global__ __launch_bounds__(256) void cvt_in(const float* __restrict__ src,
                                              bf16* __restrict__ dst) {
  // 8 elems/thread
  size_t i = ((size_t)blockIdx.x * 256 + threadIdx.x) * 8;
  float4 f0 = *(const float4*)(src + i);
  float4 f1 = *(const float4*)(src + i + 4);
  bf16_8 v;
  v[0] = (bf16)f0.x; v[1] = (bf16)f0.y; v[2] = (bf16)f0.z; v[3] = (bf16)f0.w;
  v[4] = (bf16)f1.x; v[5] = (bf16)f1.y; v[6] = (bf16)f1.z; v[7] = (bf16)f1.w;
  *(bf16_8*)(dst + i) = v;
}

__global__ __launch_bounds__(256) void convert4(const float* __restrict__ w0,
                                                const float* __restrict__ w1,
                                                const float* __restrict__ w2,
                                                const float* __restrict__ w3,
                                                bf16* __restrict__ out, int per) {
  const float* srcs[4] = {w0, w1, w2, w3};
  const float* src = srcs[blockIdx.y];
  bf16* dst = out + (size_t)blockIdx.y * per;
  int i = (blockIdx.x * 256 + threadIdx.x) * 4;
  float4 f = *(const float4*)(src + i);
  bf16_4 v;
  v[0] = (bf16)f.x; v[1] = (bf16)f.y; v[2] = (bf16)f.z; v[3] = (bf16)f.w;
  *(bf16_4*)(dst + i) = v;
}

// ---------------- GEMM: C[M][N] = A[M][K] * Bt[N][K]^T  (all-bf16 staging) ---
template <bool OUT_F32>
__global__ __launch_bounds__(256) void gemm_bt(const bf16* __restrict__ A,
                                               const bf16* __restrict__ Bt,
                                               void* __restrict__ Cp,
                                               int M, int N, int K) {
  constexpr int BM = 128, BN = 128, BK = 32;
  __shared__ alignas(16) bf16 As[BM * BK];
  __shared__ alignas(16) bf16 Bs[BN * BK];

  const int tid = threadIdx.x;
  const int wave = tid >> 6, lane = tid & 63;
  const int quad = lane >> 4, l15 = lane & 15;
  const int wm = (wave & 1) * 64, wn = (wave >> 1) * 64;
  const size_t m0 = (size_t)blockIdx.x * BM;
  const size_t n0 = (size_t)blockIdx.y * BN;

  f32_4 acc[4][4] = {};

  const size_t g_laneoff = (size_t)(lane >> 2) * K + (lane & 3) * 8;
  const bf16* Ag = A + (m0 + wave * 32) * (size_t)K + g_laneoff;
  const bf16* Bg = Bt + (n0 + wave * 32) * (size_t)K + g_laneoff;
  bf16* Al = As + wave * 32 * BK + lane * 8;
  bf16* Bl = Bs + wave * 32 * BK + lane * 8;

  for (int k0 = 0; k0 < K; k0 += BK) {
    gll16(Ag + k0, Al);
    gll16(Ag + 16 * (size_t)K + k0, Al + 16 * BK);
    gll16(Bg + k0, Bl);
    gll16(Bg + 16 * (size_t)K + k0, Bl + 16 * BK);
    __syncthreads();

    bf16_8 af[4], bfr[4];
#pragma unroll
    for (int mt = 0; mt < 4; ++mt)
      af[mt] = *(const bf16_8*)&As[(wm + mt * 16 + l15) * BK + quad * 8];
#pragma unroll
    for (int nt = 0; nt < 4; ++nt)
      bfr[nt] = *(const bf16_8*)&Bs[(wn + nt * 16 + l15) * BK + quad * 8];
#pragma unroll
    for (int mt = 0; mt < 4; ++mt)
#pragma unroll
      for (int nt = 0; nt < 4; ++nt)
        acc[mt][nt] = MFMA_16x16x32(af[mt], bfr[nt], acc[mt][nt]);
    __syncthreads();
  }

  if constexpr (OUT_F32) {
    float* C = (float*)Cp;
#pragma unroll
    for (int mt = 0; mt < 4; ++mt)
#pragma unroll
      for (int i = 0; i < 4; ++i) {
        size_t row = m0 + wm + mt * 16 + quad * 4 + i;
        float* cr = C + row * N + n0 + wn + l15;
#pragma unroll
        for (int nt = 0; nt < 4; ++nt) cr[nt * 16] = acc[mt][nt][i];
      }
  } else {
    bf16* C = (bf16*)Cp;
#pragma unroll
    for (int mt = 0; mt < 4; ++mt)
#pragma unroll
      for (int i = 0; i < 4; ++i) {
        size_t row = m0 + wm + mt * 16 + quad * 4 + i;
        bf16* cr = C + row * N + n0 + wn + l15;
#pragma unroll
        for (int nt = 0; nt < 4; ++nt) cr[nt * 16] = (bf16)acc[mt][nt][i];
      }
  }
}

// ---------------- V transpose: Vp[M][E] -> Vt[B*H][64][S] --------------------
__global__ __launch_bounds__(256) void vtrans(const bf16* __restrict__ Vp,
                                              bf16* __restrict__ Vt) {
  constexpr int S = 2048, E = 1024;
  __shared__ alignas(16) bf16 T[64 * 72];
  const int tid = threadIdx.x;
  const int s0 = blockIdx.x * 64;
  const int bh = blockIdx.y;           // b*16+h
  const int b = bh >> 4, h = bh & 15;

  {
    const int r = tid >> 2, c = (tid & 3) * 16;
    const bf16* src = Vp + ((size_t)(b * S + s0 + r)) * E + h * 64 + c;
    bf16_8 u0 = *(const bf16_8*)src;
    bf16_8 u1 = *(const bf16_8*)(src + 8);
#pragma unroll
    for (int j = 0; j < 8; ++j) T[(c + j) * 72 + r] = u0[j];
#pragma unroll
    for (int j = 0; j < 8; ++j) T[(c + 8 + j) * 72 + r] = u1[j];
  }
  __syncthreads();
  {
    const int d = tid >> 2, c2 = (tid & 3) * 16;
    bf16* dst = Vt + ((size_t)(bh * 64 + d)) * S + s0 + c2;
    *(bf16_8*)dst = *(const bf16_8*)&T[d * 72 + c2];
    *(bf16_8*)(dst + 8) = *(const bf16_8*)&T[d * 72 + c2 + 8];
  }
}

// ---------------- fused flash attention ---------------------------------------
// block = 128 q-rows of one (b,h); 4 waves x 32 q-rows; K-tiles of 64.
// Fixed-max softmax (C=10), exp2-space. LDS: QP[128x64] (Q then P), Ks, Vs.
// All rows 128B, XOR-chunk-swizzled for gll16 + conflict-free b128 frag reads.
__global__ __launch_bounds__(256, 3) void attn_fused(const bf16* __restrict__ Q,
                                                     const bf16* __restrict__ K,
                                                     const bf16* __restrict__ Vt,
                                                     const unsigned char* __restrict__ mask,
                                                     const float* __restrict__ gamma,
                                                     bf16* __restrict__ Out) {
  constexpr int S = 2048, E = 1024;
  constexpr float scale2 = 0.125f * 1.44269504f;   // (1/sqrt64)*log2(e)
  constexpr float CB = -10.0f * 1.44269504f;       // -C*log2(e)
  __shared__ alignas(16) bf16 QP[128 * 64];  // Q staging, then P tiles
  __shared__ alignas(16) bf16 Ks[64 * 64];
  __shared__ alignas(16) bf16 Vs[64 * 64];

  const int tid = threadIdx.x;
  const int wave = tid >> 6, lane = tid & 63;
  const int quad = lane >> 4, l15 = lane & 15;
  const int q0 = blockIdx.x * 128;
  const int bh = blockIdx.y;
  const int b = bh >> 4, h = bh & 15;

  // staging lane offsets (8 chunks of 16B per 128B row, XOR swizzle by row&7)
  const int lrow = lane >> 3;                    // 0..7
  const int sx = ((lane & 7) ^ lrow) * 8;        // swizzled source chunk (elems)
  const size_t koff = (size_t)lrow * E + sx;     // for Q/K ([token][E] layout)
  const size_t voff = (size_t)lrow * S + sx;     // for Vt ([d][S] layout)

  const bf16* Qg = Q + ((size_t)(b * S + q0)) * E + h * 64;
  const bf16* Kg = K + ((size_t)b * S) * E + h * 64;
  const bf16* Vg = Vt + ((size_t)bh * 64) * S;
  const unsigned char* mg = mask + (size_t)b * S;

  // ---- stage Q (128 rows x 64) once, swizzled ----
#pragma unroll
  for (int p = 0; p < 4; ++p)
    gll16(Qg + (size_t)(wave * 32 + p * 8) * E + koff,
          QP + (wave * 32 + p * 8) * 64 + lane * 8);
  __syncthreads();

  // ---- Q fragments to registers ----
  bf16_8 qf[2][2];
#pragma unroll
  for (int mt = 0; mt < 2; ++mt)
#pragma unroll
    for (int ks = 0; ks < 2; ++ks) {
      int row = wave * 32 + mt * 16 + l15;
      qf[mt][ks] = *(const bf16_8*)&QP[row * 64 + (((ks * 4 + quad) ^ (l15 & 7)) * 8)];
    }
  __syncthreads();  // all waves done reading Q before Ps overwrites

  f32_4 accO[2][4] = {};
  float rsum[2][4] = {};

  for (int kt = 0; kt < S; kt += 64) {
    __syncthreads();  // previous tile's Ks/Vs readers done
#pragma unroll
    for (int p = 0; p < 2; ++p) {
      gll16(Kg + (size_t)(kt + wave * 16 + p * 8) * E + koff,
            Ks + (wave * 16 + p * 8) * 64 + lane * 8);
      gll16(Vg + (size_t)(wave * 16 + p * 8) * S + voff + kt,
            Vs + (wave * 16 + p * 8) * 64 + lane * 8);
    }
    float bias2[4];
#pragma unroll
    for (int t = 0; t < 4; ++t)
      bias2[t] = mg[kt + t * 16 + l15] ? -1.0e30f : CB;
    __syncthreads();  // staging visible (compiler drains vmcnt before barrier)

    // ---- S = Q K^T ----
    f32_4 sAcc[2][4] = {};
#pragma unroll
    for (int ks = 0; ks < 2; ++ks) {
      bf16_8 kb[4];
#pragma unroll
      for (int t = 0; t < 4; ++t)
        kb[t] = *(const bf16_8*)&Ks[(t * 16 + l15) * 64 + (((ks * 4 + quad) ^ (l15 & 7)) * 8)];
#pragma unroll
      for (int t = 0; t < 4; ++t) {
        sAcc[0][t] = MFMA_16x16x32(qf[0][ks], kb[t], sAcc[0][t]);
        sAcc[1][t] = MFMA_16x16x32(qf[1][ks], kb[t], sAcc[1][t]);
      }
    }

    // ---- exp2 softmax (fixed max), pack pairs, write P to LDS ----
    const int ip = (l15 & 1) * 2;
    const bool evn = (l15 & 1) == 0;
#pragma unroll
    for (int mt = 0; mt < 2; ++mt)
#pragma unroll
      for (int t = 0; t < 4; ++t) {
        float e0 = exp2fast(fmaf(sAcc[mt][t][0], scale2, bias2[t]));
        float e1 = exp2fast(fmaf(sAcc[mt][t][1], scale2, bias2[t]));
        float e2 = exp2fast(fmaf(sAcc[mt][t][2], scale2, bias2[t]));
        float e3 = exp2fast(fmaf(sAcc[mt][t][3], scale2, bias2[t]));
        rsum[mt][0] += e0; rsum[mt][1] += e1;
        rsum[mt][2] += e2; rsum[mt][3] += e3;
        unsigned c01 = bfbits(e0) | (bfbits(e1) << 16);
        unsigned c23 = bfbits(e2) | (bfbits(e3) << 16);
        unsigned r01 = __shfl_xor(c01, 1);
        unsigned r23 = __shfl_xor(c23, 1);
        unsigned x = evn ? c01 : r23;
        unsigned y = evn ? r01 : c23;
        unsigned wa = (x & 0xffffu) | (y << 16);
        unsigned wb = (x >> 16) | (y & 0xffff0000u);
        int rb = wave * 32 + mt * 16 + quad * 4 + ip;
        int lch = t * 2 + (l15 >> 3);
        char* base = (char*)QP;
        *(unsigned*)(base + rb * 128 + ((lch ^ (rb & 7)) * 16) + (l15 & 6) * 2) = wa;
        *(unsigned*)(base + (rb + 1) * 128 + ((lch ^ ((rb + 1) & 7)) * 16) + (l15 & 6) * 2) = wb;
      }
    asm volatile("s_waitcnt lgkmcnt(0)" ::: "memory");  // wave-private P ready

    // ---- O += P V ----
#pragma unroll
    for (int ks = 0; ks < 2; ++ks) {
      bf16_8 pa[2];
#pragma unroll
      for (int mt = 0; mt < 2; ++mt) {
        int row = wave * 32 + mt * 16 + l15;
        pa[mt] = *(const bf16_8*)&QP[row * 64 + (((ks * 4 + quad) ^ (l15 & 7)) * 8)];
      }
#pragma unroll
      for (int t = 0; t < 4; ++t) {
        bf16_8 vb = *(const bf16_8*)&Vs[(t * 16 + l15) * 64 + (((ks * 4 + quad) ^ (l15 & 7)) * 8)];
        accO[0][t] = MFMA_16x16x32(pa[0], vb, accO[0][t]);
        accO[1][t] = MFMA_16x16x32(pa[1], vb, accO[1][t]);
      }
    }
  }

  // ---- final row-sum reduction over the 16-lane (l15) groups ----
#pragma unroll
  for (int mt = 0; mt < 2; ++mt)
#pragma unroll
    for (int i = 0; i < 4; ++i) {
      float s = rsum[mt][i];
      s += __shfl_xor(s, 1);
      s += __shfl_xor(s, 2);
      s += __shfl_xor(s, 4);
      s += __shfl_xor(s, 8);
      rsum[mt][i] = s;
    }

  const float g = gamma[h];
#pragma unroll
  for (int mt = 0; mt < 2; ++mt)
#pragma unroll
    for (int i = 0; i < 4; ++i) {
      float inv = g / rsum[mt][i];
      size_t token = (size_t)(b * S) + q0 + wave * 32 + mt * 16 + quad * 4 + i;
      bf16* orow = Out + token * E + h * 64 + l15;
#pragma unroll
      for (int t = 0; t < 4; ++t) orow[t * 16] = (bf16)(accO[mt][t][i] * inv);
    }
}

// ---------------- launch ------------------------------------------------------
extern "C" void kernel_launch(void* const* d_in, const int* in_sizes, int n_in,
                              void* d_out, int out_size, void* d_ws, size_t ws_size,
                              hipStream_t stream) {
  constexpr int Bb = 4, S = 2048, E = 1024;
  constexpr int M = Bb * S;  // 8192

  const float* q = (const float*)d_in[0];
  const float* k = (const float*)d_in[1];
  const float* v = (const float*)d_in[2];
  const unsigned char* mask = (const unsigned char*)d_in[3];
  const float* Wq = (const float*)d_in[4];
  const float* Wk = (const float*)d_in[5];
  const float* Wv = (const float*)d_in[6];
  const float* Wo = (const float*)d_in[7];
  const float* gamma = (const float*)d_in[8];

  // ws (72 MiB): Wb[0,8M) | xb/Vt[8M,24M) | Qp[24M,40M) | Kp[40M,56M) | Vp/At[56M,72M)
  char* ws = (char*)d_ws;
  bf16* Wb = (bf16*)ws;
  bf16* xb = (bf16*)(ws + ((size_t)8 << 20));   // later: Vt
  bf16* Qp = (bf16*)(ws + ((size_t)24 << 20));
  bf16* Kp = (bf16*)(ws + ((size_t)40 << 20));
  bf16* Vp = (bf16*)(ws + ((size_t)56 << 20));  // later: At

  convert4<<<dim3(1024, 4), 256, 0, stream>>>(Wq, Wk, Wv, Wo, Wb, 1 << 20);

  dim3 ggrid(M / 128, E / 128);
  cvt_in<<<4096, 256, 0, stream>>>(q, xb);
  gemm_bt<false><<<ggrid, 256, 0, stream>>>(xb, Wb, Qp, M, E, E);
  cvt_in<<<4096, 256, 0, stream>>>(k, xb);
  gemm_bt<false><<<ggrid, 256, 0, stream>>>(xb, Wb + (1 << 20), Kp, M, E, E);
  cvt_in<<<4096, 256, 0, stream>>>(v, xb);
  gemm_bt<false><<<ggrid, 256, 0, stream>>>(xb, Wb + (2 << 20), Vp, M, E, E);

  vtrans<<<dim3(32, 64), 256, 0, stream>>>(Vp, xb);  // xb now holds Vt

  bf16* At = Vp;  // Vp dead after vtrans
  attn_fused<<<dim3(16, 64), 256, 0, stream>>>(Qp, Kp, xb, mask, gamma, At);

  gemm_bt<true><<<ggrid, 256, 0, stream>>>(At, Wb + (3 << 20), d_out, M, E, E);
}

// Round 3
// 407.055 us; speedup vs baseline: 1.3678x; 1.0252x over previous
//
#include <hip/hip_runtime.h>
#include <hip/hip_bf16.h>
#include <cstdint>

typedef __bf16 bf16;
typedef __bf16 bf16_8 __attribute__((ext_vector_type(8)));
typedef __bf16 bf16_4 __attribute__((ext_vector_type(4)));
typedef float f32_4 __attribute__((ext_vector_type(4)));

#define MFMA_16x16x32(a, b, c) __builtin_amdgcn_mfma_f32_16x16x32_bf16((a), (b), (c), 0, 0, 0)

__device__ __forceinline__ void gll16(const void* g, void* l) {
  __builtin_amdgcn_global_load_lds((const __attribute__((address_space(1))) void*)g,
                                   (__attribute__((address_space(3))) void*)l, 16, 0, 0);
}

__device__ __forceinline__ float exp2fast(float x) {
#if __has_builtin(__builtin_amdgcn_exp2f)
  return __builtin_amdgcn_exp2f(x);
#else
  return __exp2f(x);
#endif
}

__device__ __forceinline__ unsigned bfbits(float x) {
  bf16 b = (bf16)x;
  return (unsigned)__builtin_bit_cast(unsigned short, b);
}

// ---------------- fp32 -> bf16 converters -----------------------------------
// one launch converts q,k,v (grid.y picks tensor)
__global__ __launch_bounds__(256) void cvt3(const float* __restrict__ s0,
                                            const float* __restrict__ s1,
                                            const float* __restrict__ s2,
                                            bf16* __restrict__ d0,
                                            bf16* __restrict__ d1,
                                            bf16* __restrict__ d2) {
  const float* srcs[3] = {s0, s1, s2};
  bf16* dsts[3] = {d0, d1, d2};
  const float* src = srcs[blockIdx.y];
  bf16* dst = dsts[blockIdx.y];
  size_t i = ((size_t)blockIdx.x * 256 + threadIdx.x) * 8;
  float4 f0 = *(const float4*)(src + i);
  float4 f1 = *(const float4*)(src + i + 4);
  bf16_8 v;
  v[0] = (bf16)f0.x; v[1] = (bf16)f0.y; v[2] = (bf16)f0.z; v[3] = (bf16)f0.w;
  v[4] = (bf16)f1.x; v[5] = (bf16)f1.y; v[6] = (bf16)f1.z; v[7] = (bf16)f1.w;
  *(bf16_8*)(dst + i) = v;
}

__global__ __launch_bounds__(256) void convert4(const float* __restrict__ w0,
                                                const float* __restrict__ w1,
                                                const float* __restrict__ w2,
                                                const float* __restrict__ w3,
                                                bf16* __restrict__ out, int per) {
  const float* srcs[4] = {w0, w1, w2, w3};
  const float* src = srcs[blockIdx.y];
  bf16* dst = out + (size_t)blockIdx.y * per;
  int i = (blockIdx.x * 256 + threadIdx.x) * 4;
  float4 f = *(const float4*)(src + i);
  bf16_4 v;
  v[0] = (bf16)f.x; v[1] = (bf16)f.y; v[2] = (bf16)f.z; v[3] = (bf16)f.w;
  *(bf16_4*)(dst + i) = v;
}

// ---------------- GEMM: C[M][N] = A[M][K] * Bt[N][K]^T, LDS double-buffered --
// rotation per k-iter: barrier -> stage(next) -> compute(cur). The barrier's
// vmcnt(0) drain covers loads issued one full compute-tile earlier.
template <bool OUT_F32>
__global__ __launch_bounds__(256) void gemm_bt(const bf16* __restrict__ A,
                                               const bf16* __restrict__ Bt,
                                               void* __restrict__ Cp,
                                               int M, int N, int K) {
  constexpr int BM = 128, BN = 128, BK = 32;
  __shared__ alignas(16) bf16 As[2][BM * BK];
  __shared__ alignas(16) bf16 Bs[2][BN * BK];

  const int tid = threadIdx.x;
  const int wave = tid >> 6, lane = tid & 63;
  const int quad = lane >> 4, l15 = lane & 15;
  const int wm = (wave & 1) * 64, wn = (wave >> 1) * 64;
  const size_t m0 = (size_t)blockIdx.x * BM;
  const size_t n0 = (size_t)blockIdx.y * BN;

  f32_4 acc[4][4] = {};

  const size_t g_laneoff = (size_t)(lane >> 2) * K + (lane & 3) * 8;
  const bf16* Ag = A + (m0 + wave * 32) * (size_t)K + g_laneoff;
  const bf16* Bg = Bt + (n0 + wave * 32) * (size_t)K + g_laneoff;
  const int l_off = wave * 32 * BK + lane * 8;

  auto stage = [&](int b, int k0) {
    gll16(Ag + k0, &As[b][l_off]);
    gll16(Ag + 16 * (size_t)K + k0, &As[b][l_off + 16 * BK]);
    gll16(Bg + k0, &Bs[b][l_off]);
    gll16(Bg + 16 * (size_t)K + k0, &Bs[b][l_off + 16 * BK]);
  };

  stage(0, 0);
  int buf = 0;
  for (int k0 = 0; k0 < K; k0 += BK, buf ^= 1) {
    __syncthreads();                       // drains stage(cur) from prev iter
    if (k0 + BK < K) stage(buf ^ 1, k0 + BK);  // in flight during compute(cur)

    bf16_8 af[4], bfr[4];
#pragma unroll
    for (int mt = 0; mt < 4; ++mt)
      af[mt] = *(const bf16_8*)&As[buf][(wm + mt * 16 + l15) * BK + quad * 8];
#pragma unroll
    for (int nt = 0; nt < 4; ++nt)
      bfr[nt] = *(const bf16_8*)&Bs[buf][(wn + nt * 16 + l15) * BK + quad * 8];
#pragma unroll
    for (int mt = 0; mt < 4; ++mt)
#pragma unroll
      for (int nt = 0; nt < 4; ++nt)
        acc[mt][nt] = MFMA_16x16x32(af[mt], bfr[nt], acc[mt][nt]);
  }

  if constexpr (OUT_F32) {
    float* C = (float*)Cp;
#pragma unroll
    for (int mt = 0; mt < 4; ++mt)
#pragma unroll
      for (int i = 0; i < 4; ++i) {
        size_t row = m0 + wm + mt * 16 + quad * 4 + i;
        float* cr = C + row * N + n0 + wn + l15;
#pragma unroll
        for (int nt = 0; nt < 4; ++nt) cr[nt * 16] = acc[mt][nt][i];
      }
  } else {
    bf16* C = (bf16*)Cp;
#pragma unroll
    for (int mt = 0; mt < 4; ++mt)
#pragma unroll
      for (int i = 0; i < 4; ++i) {
        size_t row = m0 + wm + mt * 16 + quad * 4 + i;
        bf16* cr = C + row * N + n0 + wn + l15;
#pragma unroll
        for (int nt = 0; nt < 4; ++nt) cr[nt * 16] = (bf16)acc[mt][nt][i];
      }
  }
}

// ---------------- V transpose: Vp[M][E] -> Vt[B*H][64][S] --------------------
__global__ __launch_bounds__(256) void vtrans(const bf16* __restrict__ Vp,
                                              bf16* __restrict__ Vt) {
  constexpr int S = 2048, E = 1024;
  __shared__ alignas(16) bf16 T[64 * 72];
  const int tid = threadIdx.x;
  const int s0 = blockIdx.x * 64;
  const int bh = blockIdx.y;           // b*16+h
  const int b = bh >> 4, h = bh & 15;

  {
    const int r = tid >> 2, c = (tid & 3) * 16;
    const bf16* src = Vp + ((size_t)(b * S + s0 + r)) * E + h * 64 + c;
    bf16_8 u0 = *(const bf16_8*)src;
    bf16_8 u1 = *(const bf16_8*)(src + 8);
#pragma unroll
    for (int j = 0; j < 8; ++j) T[(c + j) * 72 + r] = u0[j];
#pragma unroll
    for (int j = 0; j < 8; ++j) T[(c + 8 + j) * 72 + r] = u1[j];
  }
  __syncthreads();
  {
    const int d = tid >> 2, c2 = (tid & 3) * 16;
    bf16* dst = Vt + ((size_t)(bh * 64 + d)) * S + s0 + c2;
    *(bf16_8*)dst = *(const bf16_8*)&T[d * 72 + c2];
    *(bf16_8*)(dst + 8) = *(const bf16_8*)&T[d * 72 + c2 + 8];
  }
}

// ---------------- fused flash attention, K/V LDS double-buffered -------------
// block = 128 q-rows of one (b,h); 4 waves x 32 q-rows; K-tiles of 64.
// Fixed-max softmax (C=10), exp2-space. QP holds Q then wave-private P tiles.
// Rotation: barrier -> stage KV(next) -> compute(cur).
__global__ __launch_bounds__(256, 3) void attn_fused(const bf16* __restrict__ Q,
                                                     const bf16* __restrict__ K,
                                                     const bf16* __restrict__ Vt,
                                                     const unsigned char* __restrict__ mask,
                                                     const float* __restrict__ gamma,
                                                     bf16* __restrict__ Out) {
  constexpr int S = 2048, E = 1024;
  constexpr float scale2 = 0.125f * 1.44269504f;   // (1/sqrt64)*log2(e)
  constexpr float CB = -10.0f * 1.44269504f;       // -C*log2(e)
  __shared__ alignas(16) bf16 QP[128 * 64];        // Q staging, then P tiles
  __shared__ alignas(16) bf16 Ks[2][64 * 64];
  __shared__ alignas(16) bf16 Vs[2][64 * 64];

  const int tid = threadIdx.x;
  const int wave = tid >> 6, lane = tid & 63;
  const int quad = lane >> 4, l15 = lane & 15;
  const int q0 = blockIdx.x * 128;
  const int bh = blockIdx.y;
  const int b = bh >> 4, h = bh & 15;

  // staging lane offsets (8 chunks of 16B per 128B row, XOR swizzle by row&7)
  const int lrow = lane >> 3;                    // 0..7
  const int sx = ((lane & 7) ^ lrow) * 8;        // swizzled source chunk (elems)
  const size_t koff = (size_t)lrow * E + sx;     // for Q/K ([token][E] layout)
  const size_t voff = (size_t)lrow * S + sx;     // for Vt ([d][S] layout)

  const bf16* Qg = Q + ((size_t)(b * S + q0)) * E + h * 64;
  const bf16* Kg = K + ((size_t)b * S) * E + h * 64;
  const bf16* Vg = Vt + ((size_t)bh * 64) * S;
  const unsigned char* mg = mask + (size_t)b * S;

  auto stageKV = [&](int bf, int kt) {
#pragma unroll
    for (int p = 0; p < 2; ++p) {
      gll16(Kg + (size_t)(kt + wave * 16 + p * 8) * E + koff,
            &Ks[bf][(wave * 16 + p * 8) * 64 + lane * 8]);
      gll16(Vg + (size_t)(wave * 16 + p * 8) * S + voff + kt,
            &Vs[bf][(wave * 16 + p * 8) * 64 + lane * 8]);
    }
  };

  // ---- stage Q (128 rows x 64) + first K/V tile ----
#pragma unroll
  for (int p = 0; p < 4; ++p)
    gll16(Qg + (size_t)(wave * 32 + p * 8) * E + koff,
          QP + (wave * 32 + p * 8) * 64 + lane * 8);
  stageKV(0, 0);
  __syncthreads();  // Q + tile0 ready

  // ---- Q fragments to registers ----
  bf16_8 qf[2][2];
#pragma unroll
  for (int mt = 0; mt < 2; ++mt)
#pragma unroll
    for (int ks = 0; ks < 2; ++ks) {
      int row = wave * 32 + mt * 16 + l15;
      qf[mt][ks] = *(const bf16_8*)&QP[row * 64 + (((ks * 4 + quad) ^ (l15 & 7)) * 8)];
    }

  f32_4 accO[2][4] = {};
  float rsum[2][4] = {};

  int buf = 0;
  for (int kt = 0; kt < S; kt += 64, buf ^= 1) {
    // kt==0: protects QP (all qf reads done before P writes).
    // kt>0: drains stage(cur) issued last iter; buf(next) readers are done.
    __syncthreads();
    if (kt + 64 < S) stageKV(buf ^ 1, kt + 64);

    float bias2[4];
#pragma unroll
    for (int t = 0; t < 4; ++t)
      bias2[t] = mg[kt + t * 16 + l15] ? -1.0e30f : CB;

    // ---- S = Q K^T ----
    f32_4 sAcc[2][4] = {};
#pragma unroll
    for (int ks = 0; ks < 2; ++ks) {
      bf16_8 kb[4];
#pragma unroll
      for (int t = 0; t < 4; ++t)
        kb[t] = *(const bf16_8*)&Ks[buf][(t * 16 + l15) * 64 + (((ks * 4 + quad) ^ (l15 & 7)) * 8)];
#pragma unroll
      for (int t = 0; t < 4; ++t) {
        sAcc[0][t] = MFMA_16x16x32(qf[0][ks], kb[t], sAcc[0][t]);
        sAcc[1][t] = MFMA_16x16x32(qf[1][ks], kb[t], sAcc[1][t]);
      }
    }

    // ---- exp2 softmax (fixed max), pack pairs, write P to LDS ----
    const int ip = (l15 & 1) * 2;
    const bool evn = (l15 & 1) == 0;
#pragma unroll
    for (int mt = 0; mt < 2; ++mt)
#pragma unroll
      for (int t = 0; t < 4; ++t) {
        float e0 = exp2fast(fmaf(sAcc[mt][t][0], scale2, bias2[t]));
        float e1 = exp2fast(fmaf(sAcc[mt][t][1], scale2, bias2[t]));
        float e2 = exp2fast(fmaf(sAcc[mt][t][2], scale2, bias2[t]));
        float e3 = exp2fast(fmaf(sAcc[mt][t][3], scale2, bias2[t]));
        rsum[mt][0] += e0; rsum[mt][1] += e1;
        rsum[mt][2] += e2; rsum[mt][3] += e3;
        unsigned c01 = bfbits(e0) | (bfbits(e1) << 16);
        unsigned c23 = bfbits(e2) | (bfbits(e3) << 16);
        unsigned r01 = __shfl_xor(c01, 1);
        unsigned r23 = __shfl_xor(c23, 1);
        unsigned x = evn ? c01 : r23;
        unsigned y = evn ? r01 : c23;
        unsigned wa = (x & 0xffffu) | (y << 16);
        unsigned wb = (x >> 16) | (y & 0xffff0000u);
        int rb = wave * 32 + mt * 16 + quad * 4 + ip;
        int lch = t * 2 + (l15 >> 3);
        char* base = (char*)QP;
        *(unsigned*)(base + rb * 128 + ((lch ^ (rb & 7)) * 16) + (l15 & 6) * 2) = wa;
        *(unsigned*)(base + (rb + 1) * 128 + ((lch ^ ((rb + 1) & 7)) * 16) + (l15 & 6) * 2) = wb;
      }
    asm volatile("s_waitcnt lgkmcnt(0)" ::: "memory");  // wave-private P ready

    // ---- O += P V ----
#pragma unroll
    for (int ks = 0; ks < 2; ++ks) {
      bf16_8 pa[2];
#pragma unroll
      for (int mt = 0; mt < 2; ++mt) {
        int row = wave * 32 + mt * 16 + l15;
        pa[mt] = *(const bf16_8*)&QP[row * 64 + (((ks * 4 + quad) ^ (l15 & 7)) * 8)];
      }
#pragma unroll
      for (int t = 0; t < 4; ++t) {
        bf16_8 vb = *(const bf16_8*)&Vs[buf][(t * 16 + l15) * 64 + (((ks * 4 + quad) ^ (l15 & 7)) * 8)];
        accO[0][t] = MFMA_16x16x32(pa[0], vb, accO[0][t]);
        accO[1][t] = MFMA_16x16x32(pa[1], vb, accO[1][t]);
      }
    }
  }

  // ---- final row-sum reduction over the 16-lane (l15) groups ----
#pragma unroll
  for (int mt = 0; mt < 2; ++mt)
#pragma unroll
    for (int i = 0; i < 4; ++i) {
      float s = rsum[mt][i];
      s += __shfl_xor(s, 1);
      s += __shfl_xor(s, 2);
      s += __shfl_xor(s, 4);
      s += __shfl_xor(s, 8);
      rsum[mt][i] = s;
    }

  const float g = gamma[h];
#pragma unroll
  for (int mt = 0; mt < 2; ++mt)
#pragma unroll
    for (int i = 0; i < 4; ++i) {
      float inv = g / rsum[mt][i];
      size_t token = (size_t)(b * S) + q0 + wave * 32 + mt * 16 + quad * 4 + i;
      bf16* orow = Out + token * E + h * 64 + l15;
#pragma unroll
      for (int t = 0; t < 4; ++t) orow[t * 16] = (bf16)(accO[mt][t][i] * inv);
    }
}

// ---------------- launch ------------------------------------------------------
extern "C" void kernel_launch(void* const* d_in, const int* in_sizes, int n_in,
                              void* d_out, int out_size, void* d_ws, size_t ws_size,
                              hipStream_t stream) {
  constexpr int Bb = 4, S = 2048, E = 1024;
  constexpr int M = Bb * S;  // 8192

  const float* q = (const float*)d_in[0];
  const float* k = (const float*)d_in[1];
  const float* v = (const float*)d_in[2];
  const unsigned char* mask = (const unsigned char*)d_in[3];
  const float* Wq = (const float*)d_in[4];
  const float* Wk = (const float*)d_in[5];
  const float* Wv = (const float*)d_in[6];
  const float* Wo = (const float*)d_in[7];
  const float* gamma = (const float*)d_in[8];

  // ws (72 MiB): Wb[0,8M) | b1[8,24M) qb->Kp | b2[24,40M) kb->Vp->At |
  //              b3[40,56M) vb->Vt | b4[56,72M) Qp
  char* ws = (char*)d_ws;
  bf16* Wb = (bf16*)ws;
  bf16* b1 = (bf16*)(ws + ((size_t)8 << 20));
  bf16* b2 = (bf16*)(ws + ((size_t)24 << 20));
  bf16* b3 = (bf16*)(ws + ((size_t)40 << 20));
  bf16* b4 = (bf16*)(ws + ((size_t)56 << 20));

  convert4<<<dim3(1024, 4), 256, 0, stream>>>(Wq, Wk, Wv, Wo, Wb, 1 << 20);
  cvt3<<<dim3(4096, 3), 256, 0, stream>>>(q, k, v, b1, b2, b3);

  dim3 ggrid(M / 128, E / 128);
  gemm_bt<false><<<ggrid, 256, 0, stream>>>(b1, Wb, b4, M, E, E);             // Qp=b4
  gemm_bt<false><<<ggrid, 256, 0, stream>>>(b2, Wb + (1 << 20), b1, M, E, E); // Kp=b1
  gemm_bt<false><<<ggrid, 256, 0, stream>>>(b3, Wb + (2 << 20), b2, M, E, E); // Vp=b2

  vtrans<<<dim3(32, 64), 256, 0, stream>>>(b2, b3);                           // Vt=b3

  attn_fused<<<dim3(16, 64), 256, 0, stream>>>(b4, b1, b3, mask, gamma, b2);  // At=b2

  gemm_bt<true><<<ggrid, 256, 0, stream>>>(b2, Wb + (3 << 20), d_out, M, E, E);
}